// Round 8
// baseline (6802.814 us; speedup 1.0000x reference)
//
#include <hip/hip_runtime.h>

#define T_LEN 512
#define D_DIM 32
#define N_DIM 64
#define B_ALL 128
#define NTHR 256      // 4 waves/block; wave w owns batch rows bt*16 + w*4 .. +3

__device__ __forceinline__ float rcp_f(float x) {
#if __has_builtin(__builtin_amdgcn_rcpf)
    return __builtin_amdgcn_rcpf(x);
#else
    return 1.0f / x;
#endif
}
__device__ __forceinline__ float tanh_f(float x) {
    float e = __expf(2.0f * x);
    return 1.0f - 2.0f * rcp_f(e + 1.0f);
}
__device__ __forceinline__ float sig_f(float x) {
    return rcp_f(1.0f + __expf(-x));
}
// broadcast lane L's value of v to all lanes (VALU v_readlane, L = unroll const)
__device__ __forceinline__ float rl(float v, int L) {
    return __int_as_float(__builtin_amdgcn_readlane(__float_as_int(v), L));
}

// Block = (d, 16-batch tile), 256 threads, grid = 32 d * 8 bt = 256 (1/CU).
// WAVE-LOCAL RECURRENCE: wave w owns rows r0..r0+3; lane = n.
//   h[row][n] lives in lane n's registers; h[row][k] for the matmul comes from
//   v_readlane (k is an unroll constant) — NO LDS for h, NO sG round-trip
//   (pre[g][row][lane] is computed exactly where stage-3 consumes it), and
//   NO __syncthreads in the t-loop (waves free-run; r7's LDS-pipe wall was
//   1024 DS instr/CU-iter ~95% busy — here it's 256 full-rate b128 for W only).
// W packed in LDS as sW[k][n] = float4{Wj,Wi,Wf,Wo}[d][k][n]: one b128/lane/k.
__global__ void __launch_bounds__(NTHR, 1)
imv_lstm_scan(const float* __restrict__ x,
              const float* __restrict__ Uj, const float* __restrict__ Ui,
              const float* __restrict__ Uf, const float* __restrict__ Uo,
              const float* __restrict__ Wj, const float* __restrict__ Wi,
              const float* __restrict__ Wf, const float* __restrict__ Wo,
              const float* __restrict__ bj, const float* __restrict__ bi_,
              const float* __restrict__ bf_, const float* __restrict__ bo,
              const float* __restrict__ Fa, const float* __restrict__ Fab,
              const float* __restrict__ Fbw, const float* __restrict__ Fbb,
              const float* __restrict__ Pw, const float* __restrict__ Pb,
              float* __restrict__ wmu, float* __restrict__ wbeta)
{
    __shared__ float4 sW[N_DIM * N_DIM];   // 64 KB, [k*64 + n] = {j,i,f,o}

    const int tid  = threadIdx.x;
    const int d    = blockIdx.x & 31;
    const int bt   = blockIdx.x >> 5;
    const int wv   = tid >> 6;
    const int lane = tid & 63;             // = n
    const int row0 = bt * 16 + wv * 4;     // global batch row for j=0

    // ---- stage W[d] into LDS, gate-interleaved (coalesced per gate) ----
    for (int i = tid; i < N_DIM * N_DIM; i += NTHR) {
        int off = d * (N_DIM * N_DIM) + i;
        sW[i] = make_float4(Wj[off], Wi[off], Wf[off], Wo[off]);
    }
    __syncthreads();   // the only barrier

    const int dn = d * N_DIM + lane;
    const float u_j = Uj[dn], u_i = Ui[dn], u_f = Uf[dn], u_o = Uo[dn];
    const float cbj = bj[dn], cbi = bi_[dn], cbf = bf_[dn], cbo = bo[dn];
    const float far = Fa[dn];
    const float fab = Fab[d];

    const float* xp0 = x + (size_t)(row0 + 0) * T_LEN * D_DIM + d;
    const float* xp1 = x + (size_t)(row0 + 1) * T_LEN * D_DIM + d;
    const float* xp2 = x + (size_t)(row0 + 2) * T_LEN * D_DIM + d;
    const float* xp3 = x + (size_t)(row0 + 3) * T_LEN * D_DIM + d;

    float h0 = 0.f, h1 = 0.f, h2 = 0.f, h3 = 0.f;
    float c0 = 0.f, c1 = 0.f, c2 = 0.f, c3 = 0.f;
    float ga0 = 0.f, ga1 = 0.f, ga2 = 0.f, ga3 = 0.f;
    float as0 = 0.f, as1 = 0.f, as2 = 0.f, as3 = 0.f;

    float xc0 = xp0[0], xc1 = xp1[0], xc2 = xp2[0], xc3 = xp3[0];

    const float4* wp = sW + lane;

    #pragma unroll 1
    for (int t = 0; t < T_LEN; ++t) {
        float xn0 = 0.f, xn1 = 0.f, xn2 = 0.f, xn3 = 0.f;
        if (t + 1 < T_LEN) {                     // prefetch next x (uniform)
            xn0 = xp0[(size_t)(t + 1) * D_DIM];
            xn1 = xp1[(size_t)(t + 1) * D_DIM];
            xn2 = xp2[(size_t)(t + 1) * D_DIM];
            xn3 = xp3[(size_t)(t + 1) * D_DIM];
        }

        // ---- matmul: a{r} = {j,i,f,o} pre-partials for row r at n=lane ----
        float4 a0 = {0.f, 0.f, 0.f, 0.f};
        float4 a1 = {0.f, 0.f, 0.f, 0.f};
        float4 a2 = {0.f, 0.f, 0.f, 0.f};
        float4 a3 = {0.f, 0.f, 0.f, 0.f};
        #pragma unroll
        for (int k = 0; k < 64; ++k) {
            float4 w = wp[k * 64];               // W[k][lane] all 4 gates
            float q0 = rl(h0, k);
            float q1 = rl(h1, k);
            float q2 = rl(h2, k);
            float q3 = rl(h3, k);
            a0.x = fmaf(q0, w.x, a0.x); a0.y = fmaf(q0, w.y, a0.y);
            a0.z = fmaf(q0, w.z, a0.z); a0.w = fmaf(q0, w.w, a0.w);
            a1.x = fmaf(q1, w.x, a1.x); a1.y = fmaf(q1, w.y, a1.y);
            a1.z = fmaf(q1, w.z, a1.z); a1.w = fmaf(q1, w.w, a1.w);
            a2.x = fmaf(q2, w.x, a2.x); a2.y = fmaf(q2, w.y, a2.y);
            a2.z = fmaf(q2, w.z, a2.z); a2.w = fmaf(q2, w.w, a2.w);
            a3.x = fmaf(q3, w.x, a3.x); a3.y = fmaf(q3, w.y, a3.y);
            a3.z = fmaf(q3, w.z, a3.z); a3.w = fmaf(q3, w.w, a3.w);
        }

        // ---- gates + state + online alpha, all in-wave ----
#define ROW_STEP(A, XC, H, C, GA, AS) { \
        float jp = A.x + fmaf(XC, u_j, cbj); \
        float ip = A.y + fmaf(XC, u_i, cbi); \
        float fp = A.z + fmaf(XC, u_f, cbf); \
        float op = A.w + fmaf(XC, u_o, cbo); \
        C = fmaf(C, sig_f(fp), sig_f(ip) * tanh_f(jp)); \
        H = sig_f(op) * tanh_f(C); \
        float ps = H * far; \
        ps += __shfl_xor(ps, 1);  ps += __shfl_xor(ps, 2); \
        ps += __shfl_xor(ps, 4);  ps += __shfl_xor(ps, 8); \
        ps += __shfl_xor(ps, 16); ps += __shfl_xor(ps, 32); \
        float al = __expf(tanh_f(ps + fab)); \
        AS += al; GA = fmaf(al, H, GA); }

        ROW_STEP(a0, xc0, h0, c0, ga0, as0)
        ROW_STEP(a1, xc1, h1, c1, ga1, as1)
        ROW_STEP(a2, xc2, h2, c2, ga2, as2)
        ROW_STEP(a3, xc3, h3, c3, ga3, as3)
#undef ROW_STEP

        xc0 = xn0; xc1 = xn1; xc2 = xn2; xc3 = xn3;
    }

    // ---- epilogue: per-row mu, beta ----
    const float pwa = Pw[lane],  pwb = Pw[64 + lane];
    const float fwa = Fbw[lane], fwb = Fbw[64 + lane];
    const float pb0 = Pb[0], fb0 = Fbb[0];

#define ROW_OUT(J, H, GA, AS) { \
        float gn = GA * rcp_f(AS); \
        float pm = fmaf(gn, pwa, H * pwb); \
        float pv = fmaf(gn, fwa, H * fwb); \
        pm += __shfl_xor(pm, 1);  pm += __shfl_xor(pm, 2); \
        pm += __shfl_xor(pm, 4);  pm += __shfl_xor(pm, 8); \
        pm += __shfl_xor(pm, 16); pm += __shfl_xor(pm, 32); \
        pv += __shfl_xor(pv, 1);  pv += __shfl_xor(pv, 2); \
        pv += __shfl_xor(pv, 4);  pv += __shfl_xor(pv, 8); \
        pv += __shfl_xor(pv, 16); pv += __shfl_xor(pv, 32); \
        if (lane == 0) { \
            wmu  [(row0 + (J)) * D_DIM + d] = pm + pb0; \
            wbeta[(row0 + (J)) * D_DIM + d] = __expf(tanh_f(pv + fb0)); } }

    ROW_OUT(0, h0, ga0, as0)
    ROW_OUT(1, h1, ga1, as1)
    ROW_OUT(2, h2, ga2, as2)
    ROW_OUT(3, h3, ga3, as3)
#undef ROW_OUT
}

// beta softmax over d + weighted sum -> out[b]
__global__ void imv_finalize(const float* __restrict__ wmu,
                             const float* __restrict__ wbeta,
                             float* __restrict__ out)
{
    int b = blockIdx.x * 64 + threadIdx.x;
    if (b >= B_ALL) return;
    float s1 = 0.f, s2 = 0.f;
    for (int d = 0; d < D_DIM; ++d) {
        float be = wbeta[b * D_DIM + d];
        s1 = fmaf(be, wmu[b * D_DIM + d], s1);
        s2 += be;
    }
    out[b] = s1 / s2;
}

extern "C" void kernel_launch(void* const* d_in, const int* in_sizes, int n_in,
                              void* d_out, int out_size, void* d_ws, size_t ws_size,
                              hipStream_t stream)
{
    const float* x   = (const float*)d_in[0];
    const float* U_j = (const float*)d_in[1];
    const float* U_i = (const float*)d_in[2];
    const float* U_f = (const float*)d_in[3];
    const float* U_o = (const float*)d_in[4];
    const float* W_j = (const float*)d_in[5];
    const float* W_i = (const float*)d_in[6];
    const float* W_f = (const float*)d_in[7];
    const float* W_o = (const float*)d_in[8];
    const float* b_j = (const float*)d_in[9];
    const float* b_i = (const float*)d_in[10];
    const float* b_f = (const float*)d_in[11];
    const float* b_o = (const float*)d_in[12];
    const float* Fan  = (const float*)d_in[13];
    const float* Fanb = (const float*)d_in[14];
    const float* Fbw  = (const float*)d_in[15];
    const float* Fbb  = (const float*)d_in[16];
    const float* Phw  = (const float*)d_in[17];
    const float* Phb  = (const float*)d_in[18];

    float* wmu   = (float*)d_ws;
    float* wbeta = wmu + B_ALL * D_DIM;

    imv_lstm_scan<<<dim3(256), dim3(NTHR), 0, stream>>>(
        x, U_j, U_i, U_f, U_o, W_j, W_i, W_f, W_o,
        b_j, b_i, b_f, b_o, Fan, Fanb, Fbw, Fbb, Phw, Phb,
        wmu, wbeta);

    imv_finalize<<<dim3(2), dim3(64), 0, stream>>>(wmu, wbeta, (float*)d_out);
}

// Round 9
// 1715.803 us; speedup vs baseline: 3.9648x; 3.9648x over previous
//
#include <hip/hip_runtime.h>

#define T_LEN 512
#define D_DIM 32
#define N_DIM 64
#define B_ALL 128
#define NTHR 256      // 4 waves/block; wave w owns batch rows bt*16 + w*4 .. +3

__device__ __forceinline__ float rcp_f(float x) {
#if __has_builtin(__builtin_amdgcn_rcpf)
    return __builtin_amdgcn_rcpf(x);
#else
    return 1.0f / x;
#endif
}
__device__ __forceinline__ float tanh_f(float x) {
    float e = __expf(2.0f * x);
    return 1.0f - 2.0f * rcp_f(e + 1.0f);
}
__device__ __forceinline__ float sig_f(float x) {
    return rcp_f(1.0f + __expf(-x));
}
// broadcast lane L's value of v to all lanes; L wave-uniform (SGPR) is legal
__device__ __forceinline__ float rl(float v, int L) {
    return __int_as_float(__builtin_amdgcn_readlane(__float_as_int(v), L));
}

// Block = (d, 16-batch tile), 256 threads, grid = 256 (1 block/CU).
// Wave-local recurrence (r8 structure, VALIDATED): lane = n; h in registers,
// h[k] via v_readlane; pre[g][row][lane] computed in place; no t-loop barrier.
// r8's failure: full-k unroll hoisted 64 ds_read_b128 (256 VGPR) -> spill ->
// 11.4 GB scratch streaming. Fix: k in 4 chunks of 16, outer loop NOT
// unrolled -> max 16 float4 (64 VGPR) of W in flight; readlane lane index
// comes from an SGPR (runtime-uniform k), not an unroll constant.
__global__ void __launch_bounds__(NTHR, 1)
imv_lstm_scan(const float* __restrict__ x,
              const float* __restrict__ Uj, const float* __restrict__ Ui,
              const float* __restrict__ Uf, const float* __restrict__ Uo,
              const float* __restrict__ Wj, const float* __restrict__ Wi,
              const float* __restrict__ Wf, const float* __restrict__ Wo,
              const float* __restrict__ bj, const float* __restrict__ bi_,
              const float* __restrict__ bf_, const float* __restrict__ bo,
              const float* __restrict__ Fa, const float* __restrict__ Fab,
              const float* __restrict__ Fbw, const float* __restrict__ Fbb,
              const float* __restrict__ Pw, const float* __restrict__ Pb,
              float* __restrict__ wmu, float* __restrict__ wbeta)
{
    __shared__ float4 sW[N_DIM * N_DIM];   // 64 KB, [k*64 + n] = {j,i,f,o}

    const int tid  = threadIdx.x;
    const int d    = blockIdx.x & 31;
    const int bt   = blockIdx.x >> 5;
    const int wv   = tid >> 6;
    const int lane = tid & 63;             // = n
    const int row0 = bt * 16 + wv * 4;     // global batch row for j=0

    // ---- stage W[d] into LDS, gate-interleaved ----
    for (int i = tid; i < N_DIM * N_DIM; i += NTHR) {
        int off = d * (N_DIM * N_DIM) + i;
        sW[i] = make_float4(Wj[off], Wi[off], Wf[off], Wo[off]);
    }
    __syncthreads();   // the only barrier

    const int dn = d * N_DIM + lane;
    const float u_j = Uj[dn], u_i = Ui[dn], u_f = Uf[dn], u_o = Uo[dn];
    const float cbj = bj[dn], cbi = bi_[dn], cbf = bf_[dn], cbo = bo[dn];
    const float far = Fa[dn];
    const float fab = Fab[d];

    const float* xp0 = x + (size_t)(row0 + 0) * T_LEN * D_DIM + d;
    const float* xp1 = x + (size_t)(row0 + 1) * T_LEN * D_DIM + d;
    const float* xp2 = x + (size_t)(row0 + 2) * T_LEN * D_DIM + d;
    const float* xp3 = x + (size_t)(row0 + 3) * T_LEN * D_DIM + d;

    float h0 = 0.f, h1 = 0.f, h2 = 0.f, h3 = 0.f;
    float c0 = 0.f, c1 = 0.f, c2 = 0.f, c3 = 0.f;
    float ga0 = 0.f, ga1 = 0.f, ga2 = 0.f, ga3 = 0.f;
    float as0 = 0.f, as1 = 0.f, as2 = 0.f, as3 = 0.f;

    float xc0 = xp0[0], xc1 = xp1[0], xc2 = xp2[0], xc3 = xp3[0];

    const float4* wp = sW + lane;

    #pragma unroll 1
    for (int t = 0; t < T_LEN; ++t) {
        float xn0 = 0.f, xn1 = 0.f, xn2 = 0.f, xn3 = 0.f;
        if (t + 1 < T_LEN) {                     // prefetch next x
            xn0 = xp0[(size_t)(t + 1) * D_DIM];
            xn1 = xp1[(size_t)(t + 1) * D_DIM];
            xn2 = xp2[(size_t)(t + 1) * D_DIM];
            xn3 = xp3[(size_t)(t + 1) * D_DIM];
        }

        float4 a0 = {0.f, 0.f, 0.f, 0.f};
        float4 a1 = {0.f, 0.f, 0.f, 0.f};
        float4 a2 = {0.f, 0.f, 0.f, 0.f};
        float4 a3 = {0.f, 0.f, 0.f, 0.f};

        // ---- matmul in 4 chunks of 16 k (caps in-flight W at 64 VGPR) ----
        #pragma unroll 1
        for (int kc = 0; kc < 4; ++kc) {
            float4 w[16];
            #pragma unroll
            for (int u = 0; u < 16; ++u)
                w[u] = wp[(kc * 16 + u) * 64];
            #pragma unroll
            for (int u = 0; u < 16; ++u) {
                const int k = kc * 16 + u;       // uniform -> SGPR readlane
                float q0 = rl(h0, k);
                float q1 = rl(h1, k);
                float q2 = rl(h2, k);
                float q3 = rl(h3, k);
                a0.x = fmaf(q0, w[u].x, a0.x); a0.y = fmaf(q0, w[u].y, a0.y);
                a0.z = fmaf(q0, w[u].z, a0.z); a0.w = fmaf(q0, w[u].w, a0.w);
                a1.x = fmaf(q1, w[u].x, a1.x); a1.y = fmaf(q1, w[u].y, a1.y);
                a1.z = fmaf(q1, w[u].z, a1.z); a1.w = fmaf(q1, w[u].w, a1.w);
                a2.x = fmaf(q2, w[u].x, a2.x); a2.y = fmaf(q2, w[u].y, a2.y);
                a2.z = fmaf(q2, w[u].z, a2.z); a2.w = fmaf(q2, w[u].w, a2.w);
                a3.x = fmaf(q3, w[u].x, a3.x); a3.y = fmaf(q3, w[u].y, a3.y);
                a3.z = fmaf(q3, w[u].z, a3.z); a3.w = fmaf(q3, w[u].w, a3.w);
            }
        }

        // ---- gates + state + online alpha, all in-wave ----
#define ROW_STEP(A, XC, H, C, GA, AS) { \
        float jp = A.x + fmaf(XC, u_j, cbj); \
        float ip = A.y + fmaf(XC, u_i, cbi); \
        float fp = A.z + fmaf(XC, u_f, cbf); \
        float op = A.w + fmaf(XC, u_o, cbo); \
        C = fmaf(C, sig_f(fp), sig_f(ip) * tanh_f(jp)); \
        H = sig_f(op) * tanh_f(C); \
        float ps = H * far; \
        ps += __shfl_xor(ps, 1);  ps += __shfl_xor(ps, 2); \
        ps += __shfl_xor(ps, 4);  ps += __shfl_xor(ps, 8); \
        ps += __shfl_xor(ps, 16); ps += __shfl_xor(ps, 32); \
        float al = __expf(tanh_f(ps + fab)); \
        AS += al; GA = fmaf(al, H, GA); }

        ROW_STEP(a0, xc0, h0, c0, ga0, as0)
        ROW_STEP(a1, xc1, h1, c1, ga1, as1)
        ROW_STEP(a2, xc2, h2, c2, ga2, as2)
        ROW_STEP(a3, xc3, h3, c3, ga3, as3)
#undef ROW_STEP

        xc0 = xn0; xc1 = xn1; xc2 = xn2; xc3 = xn3;
    }

    // ---- epilogue: per-row mu, beta ----
    const float pwa = Pw[lane],  pwb = Pw[64 + lane];
    const float fwa = Fbw[lane], fwb = Fbw[64 + lane];
    const float pb0 = Pb[0], fb0 = Fbb[0];

#define ROW_OUT(J, H, GA, AS) { \
        float gn = GA * rcp_f(AS); \
        float pm = fmaf(gn, pwa, H * pwb); \
        float pv = fmaf(gn, fwa, H * fwb); \
        pm += __shfl_xor(pm, 1);  pm += __shfl_xor(pm, 2); \
        pm += __shfl_xor(pm, 4);  pm += __shfl_xor(pm, 8); \
        pm += __shfl_xor(pm, 16); pm += __shfl_xor(pm, 32); \
        pv += __shfl_xor(pv, 1);  pv += __shfl_xor(pv, 2); \
        pv += __shfl_xor(pv, 4);  pv += __shfl_xor(pv, 8); \
        pv += __shfl_xor(pv, 16); pv += __shfl_xor(pv, 32); \
        if (lane == 0) { \
            wmu  [(row0 + (J)) * D_DIM + d] = pm + pb0; \
            wbeta[(row0 + (J)) * D_DIM + d] = __expf(tanh_f(pv + fb0)); } }

    ROW_OUT(0, h0, ga0, as0)
    ROW_OUT(1, h1, ga1, as1)
    ROW_OUT(2, h2, ga2, as2)
    ROW_OUT(3, h3, ga3, as3)
#undef ROW_OUT
}

// beta softmax over d + weighted sum -> out[b]
__global__ void imv_finalize(const float* __restrict__ wmu,
                             const float* __restrict__ wbeta,
                             float* __restrict__ out)
{
    int b = blockIdx.x * 64 + threadIdx.x;
    if (b >= B_ALL) return;
    float s1 = 0.f, s2 = 0.f;
    for (int d = 0; d < D_DIM; ++d) {
        float be = wbeta[b * D_DIM + d];
        s1 = fmaf(be, wmu[b * D_DIM + d], s1);
        s2 += be;
    }
    out[b] = s1 / s2;
}

extern "C" void kernel_launch(void* const* d_in, const int* in_sizes, int n_in,
                              void* d_out, int out_size, void* d_ws, size_t ws_size,
                              hipStream_t stream)
{
    const float* x   = (const float*)d_in[0];
    const float* U_j = (const float*)d_in[1];
    const float* U_i = (const float*)d_in[2];
    const float* U_f = (const float*)d_in[3];
    const float* U_o = (const float*)d_in[4];
    const float* W_j = (const float*)d_in[5];
    const float* W_i = (const float*)d_in[6];
    const float* W_f = (const float*)d_in[7];
    const float* W_o = (const float*)d_in[8];
    const float* b_j = (const float*)d_in[9];
    const float* b_i = (const float*)d_in[10];
    const float* b_f = (const float*)d_in[11];
    const float* b_o = (const float*)d_in[12];
    const float* Fan  = (const float*)d_in[13];
    const float* Fanb = (const float*)d_in[14];
    const float* Fbw  = (const float*)d_in[15];
    const float* Fbb  = (const float*)d_in[16];
    const float* Phw  = (const float*)d_in[17];
    const float* Phb  = (const float*)d_in[18];

    float* wmu   = (float*)d_ws;
    float* wbeta = wmu + B_ALL * D_DIM;

    imv_lstm_scan<<<dim3(256), dim3(NTHR), 0, stream>>>(
        x, U_j, U_i, U_f, U_o, W_j, W_i, W_f, W_o,
        b_j, b_i, b_f, b_o, Fan, Fanb, Fbw, Fbb, Phw, Phb,
        wmu, wbeta);

    imv_finalize<<<dim3(2), dim3(64), 0, stream>>>(wmu, wbeta, (float*)d_out);
}

// Round 11
// 1472.991 us; speedup vs baseline: 4.6184x; 1.1648x over previous
//
#include <hip/hip_runtime.h>

#define T_LEN 512
#define D_DIM 32
#define N_DIM 64
#define B_ALL 128
#define NTHR 256   // 4 waves/block; wave = 2 batch rows; 2 blocks/CU

__device__ __forceinline__ float rcp_f(float x) {
#if __has_builtin(__builtin_amdgcn_rcpf)
    return __builtin_amdgcn_rcpf(x);
#else
    return 1.0f / x;
#endif
}
__device__ __forceinline__ float tanh_f(float x) {
    float e = __expf(2.0f * x);
    return 1.0f - 2.0f * rcp_f(e + 1.0f);
}
__device__ __forceinline__ float sig_f(float x) {
    return rcp_f(1.0f + __expf(-x));
}
__device__ __forceinline__ float rl(float v, int L) {
    return __int_as_float(__builtin_amdgcn_readlane(__float_as_int(v), L));
}

// Wave-local recurrence (r9 validated), occupancy doubled: wave = 2 rows ->
// 2048 waves = 2 waves/SIMD. W split: k=0..31 in 128 named SCALAR float
// registers (r10's float4 "+v" pin failed to compile: tied multi-register
// asm operands unsupported — scalars are), pinned each iteration by empty
// asm so invariant-LDS-load sinking/remat (r4/r5 failure mode) cannot fire;
// k=32..63 streamed from LDS in 4 chunks of 8. No barrier in the t-loop.
__global__ void __launch_bounds__(NTHR, 2)
imv_lstm_scan(const float* __restrict__ x,
              const float* __restrict__ Uj, const float* __restrict__ Ui,
              const float* __restrict__ Uf, const float* __restrict__ Uo,
              const float* __restrict__ Wj, const float* __restrict__ Wi,
              const float* __restrict__ Wf, const float* __restrict__ Wo,
              const float* __restrict__ bj, const float* __restrict__ bi_,
              const float* __restrict__ bf_, const float* __restrict__ bo,
              const float* __restrict__ Fa, const float* __restrict__ Fab,
              const float* __restrict__ Fbw, const float* __restrict__ Fbb,
              const float* __restrict__ Pw, const float* __restrict__ Pb,
              float* __restrict__ wmu, float* __restrict__ wbeta)
{
    __shared__ float4 sW[N_DIM * N_DIM];   // 64 KB, [k*64 + n] = {j,i,f,o}

    const int tid  = threadIdx.x;
    const int d    = blockIdx.x & 31;
    const int bt   = blockIdx.x >> 5;      // 0..15
    const int wv   = tid >> 6;
    const int lane = tid & 63;             // = n
    const int row0 = bt * 8 + wv * 2;      // this wave's two batch rows

    for (int i = tid; i < N_DIM * N_DIM; i += NTHR) {
        int off = d * (N_DIM * N_DIM) + i;
        sW[i] = make_float4(Wj[off], Wi[off], Wf[off], Wo[off]);
    }
    __syncthreads();   // the only barrier

    const int dn = d * N_DIM + lane;
    const float u_j = Uj[dn], u_i = Ui[dn], u_f = Uf[dn], u_o = Uo[dn];
    const float cbj = bj[dn], cbi = bi_[dn], cbf = bf_[dn], cbo = bo[dn];
    const float far = Fa[dn];
    const float fab = Fab[d];

    const float* xp0 = x + (size_t)(row0 + 0) * T_LEN * D_DIM + d;
    const float* xp1 = x + (size_t)(row0 + 1) * T_LEN * D_DIM + d;

    const float4* wp = sW + lane;

    // ---- k = 0..31 into 128 named scalar registers, loaded once ----
#define WDECL(K) float w##K##0, w##K##1, w##K##2, w##K##3;
#define WLOAD(K) { float4 t_ = wp[(K) * 64]; \
                   w##K##0 = t_.x; w##K##1 = t_.y; w##K##2 = t_.z; w##K##3 = t_.w; }
    WDECL(0)  WDECL(1)  WDECL(2)  WDECL(3)  WDECL(4)  WDECL(5)  WDECL(6)  WDECL(7)
    WDECL(8)  WDECL(9)  WDECL(10) WDECL(11) WDECL(12) WDECL(13) WDECL(14) WDECL(15)
    WDECL(16) WDECL(17) WDECL(18) WDECL(19) WDECL(20) WDECL(21) WDECL(22) WDECL(23)
    WDECL(24) WDECL(25) WDECL(26) WDECL(27) WDECL(28) WDECL(29) WDECL(30) WDECL(31)
    WLOAD(0)  WLOAD(1)  WLOAD(2)  WLOAD(3)  WLOAD(4)  WLOAD(5)  WLOAD(6)  WLOAD(7)
    WLOAD(8)  WLOAD(9)  WLOAD(10) WLOAD(11) WLOAD(12) WLOAD(13) WLOAD(14) WLOAD(15)
    WLOAD(16) WLOAD(17) WLOAD(18) WLOAD(19) WLOAD(20) WLOAD(21) WLOAD(22) WLOAD(23)
    WLOAD(24) WLOAD(25) WLOAD(26) WLOAD(27) WLOAD(28) WLOAD(29) WLOAD(30) WLOAD(31)
#undef WDECL
#undef WLOAD

    float h0 = 0.f, h1 = 0.f, c0 = 0.f, c1 = 0.f;
    float ga0 = 0.f, ga1 = 0.f, as0 = 0.f, as1 = 0.f;
    float xc0 = xp0[0], xc1 = xp1[0];

#define PIN4(K) "+v"(w##K##0), "+v"(w##K##1), "+v"(w##K##2), "+v"(w##K##3)

    #pragma unroll 1
    for (int t = 0; t < T_LEN; ++t) {
        // pin W scalars: asm "rewrites" them -> no remat/sinking, must stay
        asm volatile("" : PIN4(0),  PIN4(1),  PIN4(2),  PIN4(3));
        asm volatile("" : PIN4(4),  PIN4(5),  PIN4(6),  PIN4(7));
        asm volatile("" : PIN4(8),  PIN4(9),  PIN4(10), PIN4(11));
        asm volatile("" : PIN4(12), PIN4(13), PIN4(14), PIN4(15));
        asm volatile("" : PIN4(16), PIN4(17), PIN4(18), PIN4(19));
        asm volatile("" : PIN4(20), PIN4(21), PIN4(22), PIN4(23));
        asm volatile("" : PIN4(24), PIN4(25), PIN4(26), PIN4(27));
        asm volatile("" : PIN4(28), PIN4(29), PIN4(30), PIN4(31));

        float xn0 = 0.f, xn1 = 0.f;
        if (t + 1 < T_LEN) {
            xn0 = xp0[(size_t)(t + 1) * D_DIM];
            xn1 = xp1[(size_t)(t + 1) * D_DIM];
        }

        float4 a0 = {0.f, 0.f, 0.f, 0.f};
        float4 a1 = {0.f, 0.f, 0.f, 0.f};

        // ---- k = 0..31 from registers ----
#define RFMA(K) { \
        float q0 = rl(h0, K); \
        float q1 = rl(h1, K); \
        a0.x = fmaf(q0, w##K##0, a0.x); a0.y = fmaf(q0, w##K##1, a0.y); \
        a0.z = fmaf(q0, w##K##2, a0.z); a0.w = fmaf(q0, w##K##3, a0.w); \
        a1.x = fmaf(q1, w##K##0, a1.x); a1.y = fmaf(q1, w##K##1, a1.y); \
        a1.z = fmaf(q1, w##K##2, a1.z); a1.w = fmaf(q1, w##K##3, a1.w); }
        RFMA(0)  RFMA(1)  RFMA(2)  RFMA(3)  RFMA(4)  RFMA(5)  RFMA(6)  RFMA(7)
        RFMA(8)  RFMA(9)  RFMA(10) RFMA(11) RFMA(12) RFMA(13) RFMA(14) RFMA(15)
        RFMA(16) RFMA(17) RFMA(18) RFMA(19) RFMA(20) RFMA(21) RFMA(22) RFMA(23)
        RFMA(24) RFMA(25) RFMA(26) RFMA(27) RFMA(28) RFMA(29) RFMA(30) RFMA(31)
#undef RFMA

        // ---- k = 32..63 from LDS, 4 chunks of 8 (32 VGPR in flight) ----
        #pragma unroll 1
        for (int kc = 4; kc < 8; ++kc) {
            float4 w[8];
            #pragma unroll
            for (int u = 0; u < 8; ++u)
                w[u] = wp[(kc * 8 + u) * 64];
            #pragma unroll
            for (int u = 0; u < 8; ++u) {
                const int k = kc * 8 + u;        // uniform -> SGPR readlane
                float q0 = rl(h0, k);
                float q1 = rl(h1, k);
                a0.x = fmaf(q0, w[u].x, a0.x); a0.y = fmaf(q0, w[u].y, a0.y);
                a0.z = fmaf(q0, w[u].z, a0.z); a0.w = fmaf(q0, w[u].w, a0.w);
                a1.x = fmaf(q1, w[u].x, a1.x); a1.y = fmaf(q1, w[u].y, a1.y);
                a1.z = fmaf(q1, w[u].z, a1.z); a1.w = fmaf(q1, w[u].w, a1.w);
            }
        }

        // ---- gates + state + online alpha (in-wave) ----
#define ROW_STEP(A, XC, H, C, GA, AS) { \
        float jp = A.x + fmaf(XC, u_j, cbj); \
        float ip = A.y + fmaf(XC, u_i, cbi); \
        float fp = A.z + fmaf(XC, u_f, cbf); \
        float op = A.w + fmaf(XC, u_o, cbo); \
        C = fmaf(C, sig_f(fp), sig_f(ip) * tanh_f(jp)); \
        H = sig_f(op) * tanh_f(C); \
        float ps = H * far; \
        ps += __shfl_xor(ps, 1);  ps += __shfl_xor(ps, 2); \
        ps += __shfl_xor(ps, 4);  ps += __shfl_xor(ps, 8); \
        ps += __shfl_xor(ps, 16); ps += __shfl_xor(ps, 32); \
        float al = __expf(tanh_f(ps + fab)); \
        AS += al; GA = fmaf(al, H, GA); }

        ROW_STEP(a0, xc0, h0, c0, ga0, as0)
        ROW_STEP(a1, xc1, h1, c1, ga1, as1)
#undef ROW_STEP

        xc0 = xn0; xc1 = xn1;
    }
#undef PIN4

    // ---- epilogue ----
    const float pwa = Pw[lane],  pwb = Pw[64 + lane];
    const float fwa = Fbw[lane], fwb = Fbw[64 + lane];
    const float pb0 = Pb[0], fb0 = Fbb[0];

#define ROW_OUT(J, H, GA, AS) { \
        float gn = GA * rcp_f(AS); \
        float pm = fmaf(gn, pwa, H * pwb); \
        float pv = fmaf(gn, fwa, H * fwb); \
        pm += __shfl_xor(pm, 1);  pm += __shfl_xor(pm, 2); \
        pm += __shfl_xor(pm, 4);  pm += __shfl_xor(pm, 8); \
        pm += __shfl_xor(pm, 16); pm += __shfl_xor(pm, 32); \
        pv += __shfl_xor(pv, 1);  pv += __shfl_xor(pv, 2); \
        pv += __shfl_xor(pv, 4);  pv += __shfl_xor(pv, 8); \
        pv += __shfl_xor(pv, 16); pv += __shfl_xor(pv, 32); \
        if (lane == 0) { \
            wmu  [(row0 + (J)) * D_DIM + d] = pm + pb0; \
            wbeta[(row0 + (J)) * D_DIM + d] = __expf(tanh_f(pv + fb0)); } }

    ROW_OUT(0, h0, ga0, as0)
    ROW_OUT(1, h1, ga1, as1)
#undef ROW_OUT
}

// beta softmax over d + weighted sum -> out[b]
__global__ void imv_finalize(const float* __restrict__ wmu,
                             const float* __restrict__ wbeta,
                             float* __restrict__ out)
{
    int b = blockIdx.x * 64 + threadIdx.x;
    if (b >= B_ALL) return;
    float s1 = 0.f, s2 = 0.f;
    for (int d = 0; d < D_DIM; ++d) {
        float be = wbeta[b * D_DIM + d];
        s1 = fmaf(be, wmu[b * D_DIM + d], s1);
        s2 += be;
    }
    out[b] = s1 / s2;
}

extern "C" void kernel_launch(void* const* d_in, const int* in_sizes, int n_in,
                              void* d_out, int out_size, void* d_ws, size_t ws_size,
                              hipStream_t stream)
{
    const float* x   = (const float*)d_in[0];
    const float* U_j = (const float*)d_in[1];
    const float* U_i = (const float*)d_in[2];
    const float* U_f = (const float*)d_in[3];
    const float* U_o = (const float*)d_in[4];
    const float* W_j = (const float*)d_in[5];
    const float* W_i = (const float*)d_in[6];
    const float* W_f = (const float*)d_in[7];
    const float* W_o = (const float*)d_in[8];
    const float* b_j = (const float*)d_in[9];
    const float* b_i = (const float*)d_in[10];
    const float* b_f = (const float*)d_in[11];
    const float* b_o = (const float*)d_in[12];
    const float* Fan  = (const float*)d_in[13];
    const float* Fanb = (const float*)d_in[14];
    const float* Fbw  = (const float*)d_in[15];
    const float* Fbb  = (const float*)d_in[16];
    const float* Phw  = (const float*)d_in[17];
    const float* Phb  = (const float*)d_in[18];

    float* wmu   = (float*)d_ws;
    float* wbeta = wmu + B_ALL * D_DIM;

    imv_lstm_scan<<<dim3(512), dim3(NTHR), 0, stream>>>(
        x, U_j, U_i, U_f, U_o, W_j, W_i, W_f, W_o,
        b_j, b_i, b_f, b_o, Fan, Fanb, Fbw, Fbb, Phw, Phb,
        wmu, wbeta);

    imv_finalize<<<dim3(2), dim3(64), 0, stream>>>(wmu, wbeta, (float*)d_out);
}